// Round 10
// baseline (391.175 us; speedup 1.0000x reference)
//
#include <hip/hip_runtime.h>
#include <math.h>

#define LL 50
#define DD 50
#define RR 3
#define CC 10
#define SPB 16                 // samples per block (phase 2)
#define GRID_BLOCKS 2048       // = B / SPB; also covers vocab in phase 1
#define NCNT 32                // arrival counters (cache-line separated)
#define NDONE 8                // broadcast done flags
#define FLAG_STRIDE 16         // ints per flag slot (64B separation)

// ---------------- Fused single-launch kernel (cooperative, custom barrier) --
__global__ __launch_bounds__(256, 8) void fused_barrier_kernel(
    const int*   __restrict__ x,          // [B, L]
    const float* __restrict__ emb_mask,   // [B, L]
    const int*   __restrict__ combo_idx,  // [B, C, R]
    const float* __restrict__ emb_table,  // [VOCAB, D]
    const float* __restrict__ W,          // [150]
    const float* __restrict__ bvec,       // [1]
    float4*      __restrict__ dtab,       // [VOCAB] scratch
    int*         __restrict__ flags,      // barrier state (zeroed per call)
    float*       __restrict__ out,        // [B]
    int B, int vocab)
{
    __shared__ float sW[RR * DD];
    __shared__ int   s_x[SPB * LL];       // 800 ints
    __shared__ float s_m[SPB * LL];       // 800 floats

    const int tid = threadIdx.x;
    if (tid < RR * DD) sW[tid] = W[tid];
    __syncthreads();

    // ---- Phase 1: dtab[r] = (row_r.w0, row_r.w1, row_r.w2, 0) ----
    // 4 lanes per row; 2048*256/4 = 131072 rows >= vocab: single pass.
    {
        const int gtid = blockIdx.x * 256 + tid;
        const int r    = gtid >> 2;
        const int q    = gtid & 3;
        if (r < vocab) {
            const float2* p = reinterpret_cast<const float2*>(emb_table + (size_t)r * DD);
            const int s = 6 * q + (q > 0 ? 1 : 0);   // 0,7,13,19
            const int c = (q == 0) ? 7 : 6;
            float d0 = 0.f, d1 = 0.f, d2 = 0.f;
            #pragma unroll
            for (int k = 0; k < 7; ++k) {
                if (k < c) {
                    float2 e = p[s + k];
                    int j = 2 * (s + k);
                    d0 = fmaf(e.x, sW[          j], fmaf(e.y, sW[          j + 1], d0));
                    d1 = fmaf(e.x, sW[    DD  + j], fmaf(e.y, sW[    DD  + j + 1], d1));
                    d2 = fmaf(e.x, sW[2 * DD  + j], fmaf(e.y, sW[2 * DD  + j + 1], d2));
                }
            }
            d0 += __shfl_xor(d0, 1); d0 += __shfl_xor(d0, 2);
            d1 += __shfl_xor(d1, 1); d1 += __shfl_xor(d1, 2);
            d2 += __shfl_xor(d2, 1); d2 += __shfl_xor(d2, 2);
            if (q == 0) dtab[r] = make_float4(d0, d1, d2, 0.f);
        }
    }

    // ---- Stage this block's x/mask while other blocks still run phase 1 ----
    const int b0 = blockIdx.x * SPB;
    if (tid < SPB * LL / 4) {
        reinterpret_cast<int4*>(s_x)[tid] =
            reinterpret_cast<const int4*>(x + (size_t)b0 * LL)[tid];
        reinterpret_cast<float4*>(s_m)[tid] =
            reinterpret_cast<const float4*>(emb_mask + (size_t)b0 * LL)[tid];
    }

    // ---- Barrier: release dtab writes, arrive, wait for all ----
    __threadfence();                       // write-back dtab to coherence point
    __syncthreads();
    if (tid == 0)
        atomicAdd(&flags[(blockIdx.x & (NCNT - 1)) * FLAG_STRIDE], 1);

    if (blockIdx.x < NDONE) {
        // Aggregator: poll all counters until every block has arrived,
        // then publish this XCD-group's done flag.
        if (tid == 0) {
            int total;
            do {
                total = 0;
                #pragma unroll
                for (int i = 0; i < NCNT; ++i)
                    total += __hip_atomic_load(&flags[i * FLAG_STRIDE],
                                               __ATOMIC_RELAXED, __HIP_MEMORY_SCOPE_AGENT);
                if (total < GRID_BLOCKS) __builtin_amdgcn_s_sleep(4);
            } while (total < GRID_BLOCKS);
            __hip_atomic_store(&flags[(NCNT + blockIdx.x) * FLAG_STRIDE], 1,
                               __ATOMIC_RELEASE, __HIP_MEMORY_SCOPE_AGENT);
        }
    } else {
        if (tid == 0) {
            while (__hip_atomic_load(&flags[(NCNT + (blockIdx.x & (NDONE - 1))) * FLAG_STRIDE],
                                     __ATOMIC_ACQUIRE, __HIP_MEMORY_SCOPE_AGENT) == 0)
                __builtin_amdgcn_s_sleep(4);
        }
    }
    __syncthreads();
    __threadfence();                       // acquire: drop stale cached dtab lines

    // ---- Phase 2: thread-per-combo on 16 LDS-staged samples ----
    const float* dtabf = reinterpret_cast<const float*>(dtab);
    const int lane = tid & 63;
    const int sid  = ((tid >> 6) << 2) + (lane >> 4);   // 0..15
    const int c    = lane & 15;
    const int b    = b0 + sid;

    float v = 0.f;
    if (b < B && c < CC) {
        const int* cp = combo_idx + ((size_t)b * CC + c) * RR;
        int i0 = cp[0];
        int i1 = cp[1];
        int i2 = cp[2];
        const int base = sid * LL;
        int   r0 = s_x[base + i0], r1 = s_x[base + i1], r2 = s_x[base + i2];
        float m0 = s_m[base + i0], m1 = s_m[base + i1], m2 = s_m[base + i2];
        float sacc = dtabf[4 * r0 + 0] * m0
                   + dtabf[4 * r1 + 1] * m1
                   + dtabf[4 * r2 + 2] * m2
                   + bvec[0];
        v = __builtin_amdgcn_rcpf(1.0f + __expf(-sacc));
    }
    v += __shfl_down(v, 8);
    v += __shfl_down(v, 4);
    v += __shfl_down(v, 2);
    v += __shfl_down(v, 1);
    if (c == 0 && b < B) out[b] = v;
}

// ---------------- Fallback: round-8 two-kernel path ----------------
__global__ __launch_bounds__(256) void precompute_dots_kernel(
    const float* __restrict__ emb_table, const float* __restrict__ W,
    float4* __restrict__ dtab, int vocab)
{
    __shared__ float sW[RR * DD];
    if (threadIdx.x < RR * DD) sW[threadIdx.x] = W[threadIdx.x];
    __syncthreads();

    const int tid = blockIdx.x * 256 + threadIdx.x;
    const int r   = tid >> 2;
    const int q   = tid & 3;
    if (r >= vocab) return;

    const float2* p = reinterpret_cast<const float2*>(emb_table + (size_t)r * DD);
    const int s = 6 * q + (q > 0 ? 1 : 0);
    const int c = (q == 0) ? 7 : 6;

    float d0 = 0.f, d1 = 0.f, d2 = 0.f;
    #pragma unroll
    for (int k = 0; k < 7; ++k) {
        if (k < c) {
            float2 e = p[s + k];
            int j = 2 * (s + k);
            d0 = fmaf(e.x, sW[          j], fmaf(e.y, sW[          j + 1], d0));
            d1 = fmaf(e.x, sW[    DD  + j], fmaf(e.y, sW[    DD  + j + 1], d1));
            d2 = fmaf(e.x, sW[2 * DD  + j], fmaf(e.y, sW[2 * DD  + j + 1], d2));
        }
    }
    d0 += __shfl_xor(d0, 1); d0 += __shfl_xor(d0, 2);
    d1 += __shfl_xor(d1, 1); d1 += __shfl_xor(d1, 2);
    d2 += __shfl_xor(d2, 1); d2 += __shfl_xor(d2, 2);
    if (q == 0) dtab[r] = make_float4(d0, d1, d2, 0.f);
}

__global__ __launch_bounds__(256) void combo_eval_kernel(
    const int* __restrict__ x, const float* __restrict__ emb_mask,
    const int* __restrict__ combo_idx, const float* __restrict__ dtabf,
    const float* __restrict__ bvec, float* __restrict__ out, int B)
{
    __shared__ int   s_x[SPB * LL];
    __shared__ float s_m[SPB * LL];

    const int tid = threadIdx.x;
    const int b0  = blockIdx.x * SPB;

    if (tid < SPB * LL / 4) {
        reinterpret_cast<int4*>(s_x)[tid] =
            reinterpret_cast<const int4*>(x + (size_t)b0 * LL)[tid];
        reinterpret_cast<float4*>(s_m)[tid] =
            reinterpret_cast<const float4*>(emb_mask + (size_t)b0 * LL)[tid];
    }
    __syncthreads();

    const int lane = tid & 63;
    const int sid  = ((tid >> 6) << 2) + (lane >> 4);
    const int c    = lane & 15;
    const int b    = b0 + sid;

    float v = 0.f;
    if (b < B && c < CC) {
        const int* cp = combo_idx + ((size_t)b * CC + c) * RR;
        int i0 = cp[0];
        int i1 = cp[1];
        int i2 = cp[2];
        const int base = sid * LL;
        int   r0 = s_x[base + i0], r1 = s_x[base + i1], r2 = s_x[base + i2];
        float m0 = s_m[base + i0], m1 = s_m[base + i1], m2 = s_m[base + i2];
        float sacc = dtabf[4 * r0 + 0] * m0
                   + dtabf[4 * r1 + 1] * m1
                   + dtabf[4 * r2 + 2] * m2
                   + bvec[0];
        v = __builtin_amdgcn_rcpf(1.0f + __expf(-sacc));
    }
    v += __shfl_down(v, 8);
    v += __shfl_down(v, 4);
    v += __shfl_down(v, 2);
    v += __shfl_down(v, 1);
    if (c == 0 && b < B) out[b] = v;
}

extern "C" void kernel_launch(void* const* d_in, const int* in_sizes, int n_in,
                              void* d_out, int out_size, void* d_ws, size_t ws_size,
                              hipStream_t stream) {
    const int*   x         = (const int*)d_in[0];
    const float* emb_mask  = (const float*)d_in[1];
    const int*   combo_idx = (const int*)d_in[2];
    // d_in[3] = step (unused)
    const float* emb_table = (const float*)d_in[4];
    const float* W         = (const float*)d_in[5];
    const float* bvec      = (const float*)d_in[6];
    float*       out       = (float*)d_out;

    int B     = out_size;             // OUT == 1
    int vocab = in_sizes[4] / DD;     // emb_table is [VOCAB, D]

    float4* dtab = (float4*)d_ws;                       // 1.6 MB
    const size_t flag_off = ((size_t)vocab * 16 + 4095) & ~(size_t)4095;
    int* flags = (int*)((char*)d_ws + flag_off);        // 4 KB barrier state

    bool coop_ok = (B == GRID_BLOCKS * SPB) &&
                   (vocab <= GRID_BLOCKS * 256 / 4) &&
                   (ws_size >= flag_off + 4096);

    if (coop_ok) {
        hipMemsetAsync(flags, 0, 4096, stream);
        void* args[] = { (void*)&x, (void*)&emb_mask, (void*)&combo_idx,
                         (void*)&emb_table, (void*)&W, (void*)&bvec,
                         (void*)&dtab, (void*)&flags, (void*)&out,
                         (void*)&B, (void*)&vocab };
        hipError_t err = hipLaunchCooperativeKernel(
            (const void*)fused_barrier_kernel, dim3(GRID_BLOCKS), dim3(256),
            args, 0, stream);
        if (err == hipSuccess) return;
    }

    // Fallback: two-launch pipeline (round-8 best known good).
    const int pc_threads = 4 * vocab;
    precompute_dots_kernel<<<(pc_threads + 255) / 256, 256, 0, stream>>>(
        emb_table, W, dtab, vocab);
    combo_eval_kernel<<<(B + SPB - 1) / SPB, 256, 0, stream>>>(
        x, emb_mask, combo_idx, (const float*)dtab, bvec, out, B);
}

// Round 11
// 19.183 us; speedup vs baseline: 20.3918x; 20.3918x over previous
//
#include <hip/hip_runtime.h>
#include <math.h>

#define LL 50
#define DD 50
#define RR 3
#define CC 10
#define SPB 16   // samples per block in kernel 2 (4 waves * 4 samples)

// ---------------- Kernel 1: dtab[v] = (row_v.w0, row_v.w1, row_v.w2, 0) ----
// 4 lanes per vocab row (~24 waves/CU). Lane q handles float2-pairs
// [s, s+c): q0:0..6, q1:7..12, q2:13..18, q3:19..24. W staged in LDS.
__global__ __launch_bounds__(256) void precompute_dots_kernel(
    const float* __restrict__ emb_table,  // [VOCAB, D]
    const float* __restrict__ W,          // [150]
    float4*      __restrict__ dtab,       // [VOCAB]
    int vocab)
{
    __shared__ float sW[RR * DD];
    if (threadIdx.x < RR * DD) sW[threadIdx.x] = W[threadIdx.x];
    __syncthreads();

    const int tid = blockIdx.x * 256 + threadIdx.x;
    const int r   = tid >> 2;          // row
    const int q   = tid & 3;           // quarter
    if (r >= vocab) return;            // whole 4-lane group exits together

    const float2* p = reinterpret_cast<const float2*>(emb_table + (size_t)r * DD);
    const int s = 6 * q + (q > 0 ? 1 : 0);   // 0,7,13,19
    const int c = (q == 0) ? 7 : 6;

    float d0 = 0.f, d1 = 0.f, d2 = 0.f;
    #pragma unroll
    for (int k = 0; k < 7; ++k) {
        if (k < c) {
            float2 e = p[s + k];
            int j = 2 * (s + k);
            d0 = fmaf(e.x, sW[          j], fmaf(e.y, sW[          j + 1], d0));
            d1 = fmaf(e.x, sW[    DD  + j], fmaf(e.y, sW[    DD  + j + 1], d1));
            d2 = fmaf(e.x, sW[2 * DD  + j], fmaf(e.y, sW[2 * DD  + j + 1], d2));
        }
    }
    d0 += __shfl_xor(d0, 1); d0 += __shfl_xor(d0, 2);
    d1 += __shfl_xor(d1, 1); d1 += __shfl_xor(d1, 2);
    d2 += __shfl_xor(d2, 1); d2 += __shfl_xor(d2, 2);
    if (q == 0) dtab[r] = make_float4(d0, d1, d2, 0.f);
}

// ---------------- Kernel 2: thread-per-combo + LDS-staged x/mask ----------
// Block = 16 samples. Stage x/mask (16*50 ints + floats) via one int4/float4
// load per thread (fully coalesced), then lane c<10 of each 16-lane group
// evaluates one combo: combo load, 6 LDS lookups, 3 dtab component gathers
// (L2/L3-resident 1.6MB), sigmoid, 16-lane shfl tree.
__global__ __launch_bounds__(256) void combo_eval_kernel(
    const int*   __restrict__ x,          // [B, L]
    const float* __restrict__ emb_mask,   // [B, L]
    const int*   __restrict__ combo_idx,  // [B, C, R]
    const float* __restrict__ dtabf,      // [VOCAB*4]: component rr at 4*row+rr
    const float* __restrict__ bvec,       // [1]
    float*       __restrict__ out,        // [B]
    int B)
{
    __shared__ int   s_x[SPB * LL];       // 800 ints
    __shared__ float s_m[SPB * LL];       // 800 floats

    const int tid = threadIdx.x;
    const int b0  = blockIdx.x * SPB;

    // Coalesced stage: 16 samples * 50 = 800 elems = 200 vec4 per array.
    // b0*LL*4 bytes = 3200*blockIdx -> 16B-aligned. One vec4 load per thread.
    if (tid < SPB * LL / 4) {
        reinterpret_cast<int4*>(s_x)[tid] =
            reinterpret_cast<const int4*>(x + (size_t)b0 * LL)[tid];
        reinterpret_cast<float4*>(s_m)[tid] =
            reinterpret_cast<const float4*>(emb_mask + (size_t)b0 * LL)[tid];
    }
    __syncthreads();

    const int lane = tid & 63;
    const int sid  = ((tid >> 6) << 2) + (lane >> 4);   // sample in block, 0..15
    const int c    = lane & 15;                          // combo, <10 active
    const int b    = b0 + sid;

    float v = 0.f;
    if (b < B && c < CC) {
        const int* cp = combo_idx + ((size_t)b * CC + c) * RR;
        int i0 = cp[0];
        int i1 = cp[1];
        int i2 = cp[2];
        const int base = sid * LL;
        int   r0 = s_x[base + i0], r1 = s_x[base + i1], r2 = s_x[base + i2];
        float m0 = s_m[base + i0], m1 = s_m[base + i1], m2 = s_m[base + i2];
        float sacc = dtabf[4 * r0 + 0] * m0
                   + dtabf[4 * r1 + 1] * m1
                   + dtabf[4 * r2 + 2] * m2
                   + bvec[0];
        v = __builtin_amdgcn_rcpf(1.0f + __expf(-sacc));
    }
    // Sum within each 16-lane group (lanes c>=10 carry zeros).
    v += __shfl_down(v, 8);
    v += __shfl_down(v, 4);
    v += __shfl_down(v, 2);
    v += __shfl_down(v, 1);
    if (c == 0 && b < B) out[b] = v;
}

extern "C" void kernel_launch(void* const* d_in, const int* in_sizes, int n_in,
                              void* d_out, int out_size, void* d_ws, size_t ws_size,
                              hipStream_t stream) {
    const int*   x         = (const int*)d_in[0];
    const float* emb_mask  = (const float*)d_in[1];
    const int*   combo_idx = (const int*)d_in[2];
    // d_in[3] = step (unused)
    const float* emb_table = (const float*)d_in[4];
    const float* W         = (const float*)d_in[5];
    const float* bvec      = (const float*)d_in[6];
    float*       out       = (float*)d_out;

    const int B     = out_size;            // OUT == 1
    const int vocab = in_sizes[4] / DD;    // emb_table is [VOCAB, D]

    float4* dtab = (float4*)d_ws;          // 16 * VOCAB = 1.6 MB scratch

    const int pc_threads = 4 * vocab;
    precompute_dots_kernel<<<(pc_threads + 255) / 256, 256, 0, stream>>>(
        emb_table, W, dtab, vocab);

    combo_eval_kernel<<<(B + SPB - 1) / SPB, 256, 0, stream>>>(
        x, emb_mask, combo_idx, (const float*)dtab, bvec, out, B);
}